// Round 10
// baseline (95.755 us; speedup 1.0000x reference)
//
#include <hip/hip_runtime.h>
#include <hip/hip_bf16.h>

#define NN     200000
#define FEATD  64
#define BN     4096
#define DEG    32
#define PP     2048
#define EMB    64
#define EPSV   1e-8f
#define NTILES 1563    // ceil(NN/128)
#define GRIDA  768     // persistent A blocks (3 per CU)

// ws layout (float offsets)
#define WS_SC    0          // float4[NN]  {s0,s1,s2,norm}
#define WS_MISC  800000     // [0..2]=mean_pos  [4..6]=inv_pe
#define WS_LOSS  800064     // 24 slots, stride 32 floats (128B apart)
#define WS_RF    800832     // [3][BN][EMB]

// ---------------------------------------------------------------- kernel A
// sim = relu(F @ R) per node; store {dot(pe_r,sim)}_r, ||sim||.
// r8 structure (128 thr, shared 128-node swizzled tile, 8n x 8j regs) +
// T14 async-stage: persistent 768 blocks; prefetch tile t+768 into VGPRs
// BEFORE computing tile t, ds_write after the barrier. The 16 loads get the
// whole ~8k-cyc compute window to land -> stage latency hidden. 48.75 KB
// LDS -> 3 blocks/CU -> 6 waves/CU interleaving the write/compute phases.
__global__ __launch_bounds__(128) void node_precompute(
    const float* __restrict__ features, const float* __restrict__ rsim,
    const float* __restrict__ pos_embs, float4* __restrict__ node_sc)
{
    __shared__ float4 R4s[1024];       // [f][j4] 16KB
    __shared__ float4 pe4s[48];        // [r][j4]
    __shared__ float4 fT4[2048];       // [f4][col] swizzled, 32KB
    int t = threadIdx.x;
    const float4* Gf = (const float4*)features;
    const float4* rsim4 = (const float4*)rsim;

    for (int i = t; i < 1024; i += 128) R4s[i] = rsim4[i];
    if (t < 48) pe4s[t] = ((const float4*)pos_embs)[t];

    int w = t >> 6, l = t & 63;
    int g8 = l >> 3;             // node-group 0..7 (8 nodes each)
    int jo = l & 7;              // j-octant 0..7 (8 j each)
    int nb = w * 64 + g8 * 8;    // block-local node base for this thread
    int jo2 = jo * 2;            // j-quad base

    // prefetch first tile into registers
    float4 v[16];
    int tile = blockIdx.x;
    {
        int base = tile * 2048;
#pragma unroll
        for (int k = 0; k < 16; ++k)
            v[k] = Gf[min(base + k * 128 + t, NN * 16 - 1)];
    }
    __syncthreads();             // R/pe ready

    for (; tile < NTILES; tile += GRIDA) {
        // ---- write staged regs -> LDS (swizzled, r8 layout)
#pragma unroll
        for (int k = 0; k < 16; ++k) {
            int idx = k * 128 + t;
            int node = idx >> 4, f4 = idx & 15;
            int col = node ^ f4 ^ ((node >> 3) & 7);
            fT4[f4 * 128 + col] = v[k];
        }
        __syncthreads();

        // ---- prefetch next tile (lands during compute below)
        int ntile = tile + GRIDA;
        if (ntile < NTILES) {
            int base = ntile * 2048;
#pragma unroll
            for (int k = 0; k < 16; ++k)
                v[k] = Gf[min(base + k * 128 + t, NN * 16 - 1)];
        }

        // ---- compute: sim[8][8] per thread (r8 loop, proven)
        float sim[8][8];
#pragma unroll
        for (int m = 0; m < 8; ++m)
#pragma unroll
            for (int j = 0; j < 8; ++j) sim[m][j] = 0.f;

#pragma unroll 2
        for (int f4 = 0; f4 < 16; ++f4) {
            float4 fv[8];
#pragma unroll
            for (int m = 0; m < 8; ++m) {
                int n = nb + m;
                fv[m] = fT4[f4 * 128 + ((n & 63) ^ f4 ^ g8) + ((n >> 6) << 6)];
            }
#pragma unroll
            for (int u = 0; u < 4; ++u) {
                float4 r0 = R4s[(f4 * 4 + u) * 16 + jo2];
                float4 r1 = R4s[(f4 * 4 + u) * 16 + jo2 + 1];
#pragma unroll
                for (int m = 0; m < 8; ++m) {
                    float x = (u == 0) ? fv[m].x : (u == 1) ? fv[m].y
                            : (u == 2) ? fv[m].z : fv[m].w;
                    sim[m][0] += x * r0.x; sim[m][1] += x * r0.y;
                    sim[m][2] += x * r0.z; sim[m][3] += x * r0.w;
                    sim[m][4] += x * r1.x; sim[m][5] += x * r1.y;
                    sim[m][6] += x * r1.z; sim[m][7] += x * r1.w;
                }
            }
        }

        // ---- epilogue on this thread's 8-j slice (r8, proven)
        float red[8][4];
#pragma unroll
        for (int m = 0; m < 8; ++m) {
            float q = 0.f, s0 = 0.f, s1 = 0.f, s2 = 0.f;
#pragma unroll
            for (int j4 = 0; j4 < 2; ++j4) {
                float4 p0 = pe4s[jo2 + j4];
                float4 p1 = pe4s[16 + jo2 + j4];
                float4 p2 = pe4s[32 + jo2 + j4];
#pragma unroll
                for (int c = 0; c < 4; ++c) {
                    float vv = fmaxf(sim[m][j4 * 4 + c], 0.f);
                    float pp0 = (c==0)?p0.x:(c==1)?p0.y:(c==2)?p0.z:p0.w;
                    float pp1 = (c==0)?p1.x:(c==1)?p1.y:(c==2)?p1.z:p1.w;
                    float pp2 = (c==0)?p2.x:(c==1)?p2.y:(c==2)?p2.z:p2.w;
                    q += vv * vv; s0 += vv * pp0; s1 += vv * pp1; s2 += vv * pp2;
                }
            }
            red[m][0] = s0; red[m][1] = s1; red[m][2] = s2; red[m][3] = q;
        }
#pragma unroll
        for (int o = 1; o < 8; o <<= 1)
#pragma unroll
            for (int m = 0; m < 8; ++m)
#pragma unroll
                for (int c = 0; c < 4; ++c)
                    red[m][c] += __shfl_xor(red[m][c], o);

        float r0 = 0.f, r1 = 0.f, r2 = 0.f, rq = 0.f;
#pragma unroll
        for (int m = 0; m < 8; ++m) {
            bool pick = (jo == m);
            r0 = pick ? red[m][0] : r0;
            r1 = pick ? red[m][1] : r1;
            r2 = pick ? red[m][2] : r2;
            rq = pick ? red[m][3] : rq;
        }
        int node = tile * 128 + nb + jo;
        if (node < NN)
            node_sc[node] = make_float4(r0, r1, r2, sqrtf(rq));

        __syncthreads();   // all reads of fT4 done before next overwrite
    }
}

// ---------------------------------------------------------------- kernel B
// pe inverse norms, mean(pos_scores) per relation, zero loss slots.
__global__ __launch_bounds__(1024) void pos_stats(
    const int* __restrict__ pos_nodes, const float4* __restrict__ node_sc,
    const float* __restrict__ pos_embs, float* __restrict__ misc,
    float* __restrict__ lossacc)
{
    __shared__ float invpe_s[3];
    __shared__ float wsum[16][3];
    int t = threadIdx.x, wv = t >> 6, lane = t & 63;

    if (t < 24) lossacc[t * 32] = 0.f;           // zero spread loss slots

    // pe norms: waves 0..2 each own one pos_emb row
    float pv = (t < 192) ? pos_embs[t] : 0.f;
    float q = pv * pv;
#pragma unroll
    for (int off = 32; off; off >>= 1) q += __shfl_down(q, off);
    if (t < 192 && lane == 0) {
        float inv = 1.f / fmaxf(sqrtf(q), EPSV);
        invpe_s[wv] = inv;
        misc[4 + wv] = inv;
    }
    __syncthreads();

    float i0 = invpe_s[0], i1 = invpe_s[1], i2 = invpe_s[2];
    float s0 = 0.f, s1 = 0.f, s2 = 0.f;
    for (int p = t; p < PP; p += 1024) {
        int n = pos_nodes[p];
        float4 sc = node_sc[n];
        float invn = 1.f / fmaxf(sc.w, EPSV);
        s0 += sc.x * i0 * invn;
        s1 += sc.y * i1 * invn;
        s2 += sc.z * i2 * invn;
    }
#pragma unroll
    for (int off = 32; off; off >>= 1) {
        s0 += __shfl_down(s0, off);
        s1 += __shfl_down(s1, off);
        s2 += __shfl_down(s2, off);
    }
    if (lane == 0) { wsum[wv][0] = s0; wsum[wv][1] = s1; wsum[wv][2] = s2; }
    __syncthreads();
    if (t < 3) {
        float s = 0.f;
        for (int w = 0; w < 16; ++w) s += wsum[w][t];
        misc[t] = s / (float)PP;
    }
}

// ---------------------------------------------------------------- kernel C
// One wave per (b, r): score 32 neighbors, stable top-k, parallel 16-row
// feature aggregate, rfeat = relu(agg @ W_r) via uniform-LDS broadcast.
__global__ __launch_bounds__(256) void relation_agg(
    const int* __restrict__ n1, const int* __restrict__ n2, const int* __restrict__ n3,
    const float* __restrict__ features, const float4* __restrict__ node_sc,
    const float* __restrict__ W1, const float* __restrict__ W2, const float* __restrict__ W3,
    const float* __restrict__ misc, float* __restrict__ lossacc,
    float* __restrict__ rfeat, const int* __restrict__ smp)
{
    int r = blockIdx.y;
    const int*   neigh = (r == 0) ? n1 : (r == 1) ? n2 : n3;
    const float* W     = (r == 0) ? W1 : (r == 1) ? W2 : W3;
    int k = smp[0];
    int t = threadIdx.x;
    int wv = t >> 6, lane = t & 63;
    int b = blockIdx.x * 4 + wv;
    float inv_pe   = misc[4 + r];
    float mean_pos = misc[r];

    __shared__ int sel_ids[4][32];
    __shared__ float4 aggl[4][16];

    // ---- score phase (lanes 0-31)
    float s = -1e30f;
    int   n = 0;
    if (lane < 32) {
        n = neigh[b * DEG + lane];
        float4 sc = node_sc[n];
        float num = (r == 0) ? sc.x : (r == 1) ? sc.y : sc.z;
        s = num * inv_pe / fmaxf(sc.w, EPSV);
    }
    // stable rank among 32 scores (ties -> lower index), matches lax.top_k
    int cnt = 0;
#pragma unroll
    for (int d2 = 0; d2 < 32; ++d2) {
        float v = __shfl(s, d2);
        cnt += ((v > s) || (v == s && d2 < lane)) ? 1 : 0;
    }
    bool sel = (lane < 32) && (cnt < k);
    if (sel) sel_ids[wv][cnt] = n;       // rank = unique slot in [0,k)

    float lv = sel ? (s - mean_pos) * (s - mean_pos) : 0.f;
#pragma unroll
    for (int off = 32; off; off >>= 1) lv += __shfl_down(lv, off);
    if (lane == 0)
        atomicAdd(&lossacc[(r * 8 + (blockIdx.x & 7)) * 32], lv);
    // no __syncthreads: sel_ids producer/consumer are the same wave (lgkmcnt)

    // ---- aggregate phase: 16 lanes per row, 4 rows per load wavefront
    const float4* F = (const float4*)features;
    int col   = lane & 15;           // float4 index within a 64-float row
    int rbase = lane >> 4;           // 0..3
    float4 a = make_float4(0.f, 0.f, 0.f, 0.f);
    if (k == 16) {
        int nid0 = sel_ids[wv][rbase];
        int nid1 = sel_ids[wv][rbase + 4];
        int nid2 = sel_ids[wv][rbase + 8];
        int nid3 = sel_ids[wv][rbase + 12];
        float4 v0 = F[(size_t)nid0 * 16 + col];
        float4 v1 = F[(size_t)nid1 * 16 + col];
        float4 v2 = F[(size_t)nid2 * 16 + col];
        float4 v3 = F[(size_t)nid3 * 16 + col];
        a.x = v0.x + v1.x + v2.x + v3.x;
        a.y = v0.y + v1.y + v2.y + v3.y;
        a.z = v0.z + v1.z + v2.z + v3.z;
        a.w = v0.w + v1.w + v2.w + v3.w;
    } else {
        for (int row0 = 0; row0 < k; row0 += 4) {
            int row = row0 + rbase;
            if (row < k) {
                int nid = sel_ids[wv][row];
                float4 v = F[(size_t)nid * 16 + col];
                a.x += v.x; a.y += v.y; a.z += v.z; a.w += v.w;
            }
        }
    }
    // allreduce across the 4 row-groups (xor 16, 32)
#pragma unroll
    for (int off = 16; off <= 32; off <<= 1) {
        a.x += __shfl_xor(a.x, off);
        a.y += __shfl_xor(a.y, off);
        a.z += __shfl_xor(a.z, off);
        a.w += __shfl_xor(a.w, off);
    }
    float inv_k = 1.f / (float)k;
    a.x *= inv_k; a.y *= inv_k; a.z *= inv_k; a.w *= inv_k;

    // publish agg to LDS (lanes 0-15 hold cols 0..15)
    if (lane < 16) aggl[wv][lane] = a;
    // same-wave producer/consumer: compiler inserts lgkmcnt, no barrier

    // ---- rfeat[e=lane] = relu(sum_j agg[j] * W[j][e]) via uniform LDS reads
    float acc = 0.f;
#pragma unroll
    for (int j4 = 0; j4 < 16; ++j4) {
        float4 ag = aggl[wv][j4];            // wave-uniform -> broadcast
        acc += ag.x * W[(j4 * 4 + 0) * EMB + lane]
             + ag.y * W[(j4 * 4 + 1) * EMB + lane]
             + ag.z * W[(j4 * 4 + 2) * EMB + lane]
             + ag.w * W[(j4 * 4 + 3) * EMB + lane];
    }
    rfeat[((size_t)r * BN + b) * EMB + lane] = fmaxf(acc, 0.f);
}

// ---------------------------------------------------------------- kernel D
// combined[e][b] = relu(cat[b] . weight[:,e]).
// 512 blocks, b-tile = 8. weight read from GLOBAL, coalesced (lane = e,
// row stride 256B); cat in LDS (uniform broadcast).
#define CSTRIDE 264
__global__ __launch_bounds__(256) void final_mm(
    const int* __restrict__ nodes, const float* __restrict__ features,
    const float* __restrict__ rfeat, const float* __restrict__ weight,
    const float* __restrict__ lossacc, const int* __restrict__ smp,
    float* __restrict__ out)
{
    __shared__ float cat_b[8 * CSTRIDE];   // cat_b[bb][i]
    __shared__ float trans[8 * 65];        // output transpose tile
    __shared__ float ls[24];
    int t = threadIdx.x;
    int b0 = blockIdx.x * 8;

    if (blockIdx.x == 0 && t < 24) ls[t] = lossacc[t * 32];

    // stage cat columns: center features then 3 rfeat blocks
    for (int idx = t; idx < 512; idx += 256) {
        int bb = idx >> 6, f = idx & 63;
        cat_b[bb * CSTRIDE + f] = features[(size_t)nodes[b0 + bb] * FEATD + f];
    }
#pragma unroll
    for (int r = 0; r < 3; ++r)
        for (int idx = t; idx < 512; idx += 256) {
            int bb = idx >> 6, j = idx & 63;
            cat_b[bb * CSTRIDE + 64 + r * 64 + j] =
                rfeat[((size_t)r * BN + b0 + bb) * EMB + j];
        }
    __syncthreads();

    int wv = t >> 6, lane = t & 63;     // lane = e
    int bb0 = wv * 2;
    float acc0 = 0.f, acc1 = 0.f;
    const float* c0p = &cat_b[bb0 * CSTRIDE];
    const float* c1p = &cat_b[(bb0 + 1) * CSTRIDE];
    for (int i0 = 0; i0 < 256; i0 += 16) {
        float w[16];
#pragma unroll
        for (int u = 0; u < 16; ++u)
            w[u] = weight[(i0 + u) * EMB + lane];   // coalesced
#pragma unroll
        for (int u = 0; u < 16; ++u) {
            acc0 += w[u] * c0p[i0 + u];             // uniform LDS broadcast
            acc1 += w[u] * c1p[i0 + u];
        }
    }
    trans[bb0 * 65 + lane]       = fmaxf(acc0, 0.f);
    trans[(bb0 + 1) * 65 + lane] = fmaxf(acc1, 0.f);
    __syncthreads();

    // store: out[e][b0..b0+8]
    for (int idx = t; idx < 512; idx += 256) {
        int e = idx >> 3, bb = idx & 7;
        out[(size_t)e * BN + b0 + bb] = trans[bb * 65 + e];
    }

    if (blockIdx.x == 0 && t == 0) {
        int k = smp[0];
        float s = 0.f;
        for (int i = 0; i < 24; ++i) s += ls[i];
        out[(size_t)EMB * BN] = s / (3.f * (float)BN * (float)k);
    }
}

// ----------------------------------------------------------------
extern "C" void kernel_launch(void* const* d_in, const int* in_sizes, int n_in,
                              void* d_out, int out_size, void* d_ws, size_t ws_size,
                              hipStream_t stream) {
    const int*   nodes     = (const int*)  d_in[0];
    // d_in[1] labels: unused
    const int*   neigh1    = (const int*)  d_in[2];
    const int*   neigh2    = (const int*)  d_in[3];
    const int*   neigh3    = (const int*)  d_in[4];
    const int*   pos_nodes = (const int*)  d_in[5];
    const float* features  = (const float*)d_in[6];
    const float* weight    = (const float*)d_in[7];
    const float* rsim      = (const float*)d_in[8];
    const float* pos_embs  = (const float*)d_in[9];
    const float* W1        = (const float*)d_in[10];
    const float* W2        = (const float*)d_in[11];
    const float* W3        = (const float*)d_in[12];
    const int*   smp       = (const int*)  d_in[13];
    float* out = (float*)d_out;
    float* ws  = (float*)d_ws;

    float4* node_sc = (float4*)(ws + WS_SC);
    float*  misc    = ws + WS_MISC;
    float*  lossacc = ws + WS_LOSS;
    float*  rfeat   = ws + WS_RF;

    node_precompute<<<dim3(GRIDA), dim3(128), 0, stream>>>(
        features, rsim, pos_embs, node_sc);
    pos_stats<<<dim3(1), dim3(1024), 0, stream>>>(
        pos_nodes, node_sc, pos_embs, misc, lossacc);
    relation_agg<<<dim3(BN / 4, 3), dim3(256), 0, stream>>>(
        neigh1, neigh2, neigh3, features, node_sc, W1, W2, W3,
        misc, lossacc, rfeat, smp);
    final_mm<<<dim3(BN / 8), dim3(256), 0, stream>>>(
        nodes, features, rfeat, weight, lossacc, smp, out);
}

// Round 11
// 86.131 us; speedup vs baseline: 1.1117x; 1.1117x over previous
//
#include <hip/hip_runtime.h>
#include <hip/hip_bf16.h>

#define NN     200000
#define FEATD  64
#define BN     4096
#define DEG    32
#define PP     2048
#define EMB    64
#define EPSV   1e-8f
#define NCHUNK 6250        // NN / 32 exactly
#define NWAVES 2048        // 512 blocks x 4 waves

// ws layout (float offsets)
#define WS_SC    0          // float4[NN]  {s0,s1,s2,norm}
#define WS_MISC  800000     // [0..2]=mean_pos  [4..6]=inv_pe
#define WS_LOSS  800064     // 24 slots, stride 32 floats (128B apart)
#define WS_RF    800832     // [3][BN][EMB]

// ---------------------------------------------------------------- kernel A
// sim = relu(F @ R) per node; store {dot(pe_r,sim)}_r, ||sim||.
// Wave-private 32-node chunks, DOUBLE-BUFFERED global_load_lds staging
// (zero staging VGPRs -> no spill; zero barriers; counted vmcnt(8) keeps the
// next chunk's loads in flight across the whole compute phase).
// Thread = 4 nodes x 8 j. LDS swizzle col = n ^ ((n>>2)&7): 8-lane broadcast
// groups hit 8 distinct bank-quads -> conflict-free. R/pe from global (L1).
// LDS = 64KB exactly -> 2 blocks/CU -> 8 waves/CU.
__global__ __launch_bounds__(256) void node_precompute(
    const float* __restrict__ features, const float* __restrict__ rsim,
    const float* __restrict__ pos_embs, float4* __restrict__ node_sc)
{
    __shared__ float4 ftile[4][2][512];   // [wave][buf][f4*32+col], 64KB
    int t = threadIdx.x;
    int w = t >> 6, l = t & 63;
    int g = l >> 3, jo = l & 7;
    const float4* Gf  = (const float4*)features;
    const float4* R4  = (const float4*)rsim;
    const float4* PE4 = (const float4*)pos_embs;

    // hoisted pe slices for this lane's 8 j's (j = jo*8 .. jo*8+7)
    float4 pe0a = PE4[jo * 2],      pe0b = PE4[jo * 2 + 1];
    float4 pe1a = PE4[16 + jo * 2], pe1b = PE4[16 + jo * 2 + 1];
    float4 pe2a = PE4[32 + jo * 2], pe2b = PE4[32 + jo * 2 + 1];

    // staging source: inverse of col = n ^ ((n>>2)&7)  (bijective on 0..31)
    int col = l & 31;
    int b4 = (col >> 4) & 1, b3 = (col >> 3) & 1;
    int b2 = ((col >> 2) & 1) ^ b4;
    int b1 = ((col >> 1) & 1) ^ b3;
    int b0 = (col & 1) ^ b2;
    int nloc  = (b4 << 4) | (b3 << 3) | (b2 << 2) | (b1 << 1) | b0;
    int fhalf = l >> 5;

    // compute-side swizzled cols for this thread's 4 nodes (n = g*4+m)
    int fcol[4];
#pragma unroll
    for (int m = 0; m < 4; ++m) fcol[m] = (g * 4 + m) ^ g;

    int wid = blockIdx.x * 4 + w;

    auto STAGE = [&](int c, int buf) {
        const float4* src = Gf + (size_t)(c * 32 + nloc) * 16 + fhalf;
        float4* dst = &ftile[w][buf][0];
#pragma unroll
        for (int s = 0; s < 8; ++s)
            __builtin_amdgcn_global_load_lds(
                (const void*)(src + s * 2), (void*)(dst + s * 64), 16, 0, 0);
    };

    auto COMPUTE = [&](int c, int buf) {
        const float4* fb = &ftile[w][buf][0];
        float sim[4][8];
#pragma unroll
        for (int m = 0; m < 4; ++m)
#pragma unroll
            for (int j = 0; j < 8; ++j) sim[m][j] = 0.f;

#pragma unroll 2
        for (int f4 = 0; f4 < 16; ++f4) {
            float4 fv[4];
#pragma unroll
            for (int m = 0; m < 4; ++m) fv[m] = fb[f4 * 32 + fcol[m]];
#pragma unroll
            for (int u = 0; u < 4; ++u) {
                float4 ra = R4[(f4 * 4 + u) * 16 + jo * 2];
                float4 rb = R4[(f4 * 4 + u) * 16 + jo * 2 + 1];
#pragma unroll
                for (int m = 0; m < 4; ++m) {
                    float x = (u == 0) ? fv[m].x : (u == 1) ? fv[m].y
                            : (u == 2) ? fv[m].z : fv[m].w;
                    sim[m][0] += x * ra.x; sim[m][1] += x * ra.y;
                    sim[m][2] += x * ra.z; sim[m][3] += x * ra.w;
                    sim[m][4] += x * rb.x; sim[m][5] += x * rb.y;
                    sim[m][6] += x * rb.z; sim[m][7] += x * rb.w;
                }
            }
        }

        float red[4][4];
#pragma unroll
        for (int m = 0; m < 4; ++m) {
            float v0 = fmaxf(sim[m][0], 0.f), v1 = fmaxf(sim[m][1], 0.f);
            float v2 = fmaxf(sim[m][2], 0.f), v3 = fmaxf(sim[m][3], 0.f);
            float v4 = fmaxf(sim[m][4], 0.f), v5 = fmaxf(sim[m][5], 0.f);
            float v6 = fmaxf(sim[m][6], 0.f), v7 = fmaxf(sim[m][7], 0.f);
            red[m][3] = v0*v0 + v1*v1 + v2*v2 + v3*v3
                      + v4*v4 + v5*v5 + v6*v6 + v7*v7;
            red[m][0] = v0*pe0a.x + v1*pe0a.y + v2*pe0a.z + v3*pe0a.w
                      + v4*pe0b.x + v5*pe0b.y + v6*pe0b.z + v7*pe0b.w;
            red[m][1] = v0*pe1a.x + v1*pe1a.y + v2*pe1a.z + v3*pe1a.w
                      + v4*pe1b.x + v5*pe1b.y + v6*pe1b.z + v7*pe1b.w;
            red[m][2] = v0*pe2a.x + v1*pe2a.y + v2*pe2a.z + v3*pe2a.w
                      + v4*pe2b.x + v5*pe2b.y + v6*pe2b.z + v7*pe2b.w;
        }
#pragma unroll
        for (int o = 1; o < 8; o <<= 1)
#pragma unroll
            for (int m = 0; m < 4; ++m)
#pragma unroll
                for (int qq = 0; qq < 4; ++qq)
                    red[m][qq] += __shfl_xor(red[m][qq], o);

        if (jo < 4) {    // lane jo writes node g*4+jo (static-index select)
            float o0 = (jo==0)?red[0][0]:(jo==1)?red[1][0]:(jo==2)?red[2][0]:red[3][0];
            float o1 = (jo==0)?red[0][1]:(jo==1)?red[1][1]:(jo==2)?red[2][1]:red[3][1];
            float o2 = (jo==0)?red[0][2]:(jo==1)?red[1][2]:(jo==2)?red[2][2]:red[3][2];
            float oq = (jo==0)?red[0][3]:(jo==1)?red[1][3]:(jo==2)?red[2][3]:red[3][3];
            node_sc[c * 32 + g * 4 + jo] = make_float4(o0, o1, o2, sqrtf(oq));
        }
    };

    // prologue: fill both buffers (order pinned)
    STAGE(wid, 0);
    __builtin_amdgcn_sched_barrier(0);
    STAGE(wid + 2048, 1);
    __builtin_amdgcn_sched_barrier(0);

#pragma unroll 1
    for (int i = 0; i < 4; ++i) {
        int c = wid + i * 2048;
        if (c >= NCHUNK) break;
        if (c + 2048 < NCHUNK)      // a younger stage is in flight: keep it
            asm volatile("s_waitcnt vmcnt(8)" ::: "memory");
        else                        // nothing younger: full drain
            asm volatile("s_waitcnt vmcnt(0)" ::: "memory");
        COMPUTE(c, i & 1);
        int cp = c + 4096;          // prefetch 2 ahead into the buffer just freed
        if (cp < NCHUNK) STAGE(cp, i & 1);
    }
}

// ---------------------------------------------------------------- kernel B
// pe inverse norms, mean(pos_scores) per relation, zero loss slots.
__global__ __launch_bounds__(1024) void pos_stats(
    const int* __restrict__ pos_nodes, const float4* __restrict__ node_sc,
    const float* __restrict__ pos_embs, float* __restrict__ misc,
    float* __restrict__ lossacc)
{
    __shared__ float invpe_s[3];
    __shared__ float wsum[16][3];
    int t = threadIdx.x, wv = t >> 6, lane = t & 63;

    if (t < 24) lossacc[t * 32] = 0.f;           // zero spread loss slots

    // pe norms: waves 0..2 each own one pos_emb row
    float pv = (t < 192) ? pos_embs[t] : 0.f;
    float q = pv * pv;
#pragma unroll
    for (int off = 32; off; off >>= 1) q += __shfl_down(q, off);
    if (t < 192 && lane == 0) {
        float inv = 1.f / fmaxf(sqrtf(q), EPSV);
        invpe_s[wv] = inv;
        misc[4 + wv] = inv;
    }
    __syncthreads();

    float i0 = invpe_s[0], i1 = invpe_s[1], i2 = invpe_s[2];
    float s0 = 0.f, s1 = 0.f, s2 = 0.f;
    for (int p = t; p < PP; p += 1024) {
        int n = pos_nodes[p];
        float4 sc = node_sc[n];
        float invn = 1.f / fmaxf(sc.w, EPSV);
        s0 += sc.x * i0 * invn;
        s1 += sc.y * i1 * invn;
        s2 += sc.z * i2 * invn;
    }
#pragma unroll
    for (int off = 32; off; off >>= 1) {
        s0 += __shfl_down(s0, off);
        s1 += __shfl_down(s1, off);
        s2 += __shfl_down(s2, off);
    }
    if (lane == 0) { wsum[wv][0] = s0; wsum[wv][1] = s1; wsum[wv][2] = s2; }
    __syncthreads();
    if (t < 3) {
        float s = 0.f;
        for (int w = 0; w < 16; ++w) s += wsum[w][t];
        misc[t] = s / (float)PP;
    }
}

// ---------------------------------------------------------------- kernel C
// One wave per (b, r): score 32 neighbors, stable top-k, parallel 16-row
// feature aggregate, rfeat = relu(agg @ W_r) via uniform-LDS broadcast.
__global__ __launch_bounds__(256) void relation_agg(
    const int* __restrict__ n1, const int* __restrict__ n2, const int* __restrict__ n3,
    const float* __restrict__ features, const float4* __restrict__ node_sc,
    const float* __restrict__ W1, const float* __restrict__ W2, const float* __restrict__ W3,
    const float* __restrict__ misc, float* __restrict__ lossacc,
    float* __restrict__ rfeat, const int* __restrict__ smp)
{
    int r = blockIdx.y;
    const int*   neigh = (r == 0) ? n1 : (r == 1) ? n2 : n3;
    const float* W     = (r == 0) ? W1 : (r == 1) ? W2 : W3;
    int k = smp[0];
    int t = threadIdx.x;
    int wv = t >> 6, lane = t & 63;
    int b = blockIdx.x * 4 + wv;
    float inv_pe   = misc[4 + r];
    float mean_pos = misc[r];

    __shared__ int sel_ids[4][32];
    __shared__ float4 aggl[4][16];

    // ---- score phase (lanes 0-31)
    float s = -1e30f;
    int   n = 0;
    if (lane < 32) {
        n = neigh[b * DEG + lane];
        float4 sc = node_sc[n];
        float num = (r == 0) ? sc.x : (r == 1) ? sc.y : sc.z;
        s = num * inv_pe / fmaxf(sc.w, EPSV);
    }
    // stable rank among 32 scores (ties -> lower index), matches lax.top_k
    int cnt = 0;
#pragma unroll
    for (int d2 = 0; d2 < 32; ++d2) {
        float v = __shfl(s, d2);
        cnt += ((v > s) || (v == s && d2 < lane)) ? 1 : 0;
    }
    bool sel = (lane < 32) && (cnt < k);
    if (sel) sel_ids[wv][cnt] = n;       // rank = unique slot in [0,k)

    float lv = sel ? (s - mean_pos) * (s - mean_pos) : 0.f;
#pragma unroll
    for (int off = 32; off; off >>= 1) lv += __shfl_down(lv, off);
    if (lane == 0)
        atomicAdd(&lossacc[(r * 8 + (blockIdx.x & 7)) * 32], lv);
    // no __syncthreads: sel_ids producer/consumer are the same wave (lgkmcnt)

    // ---- aggregate phase: 16 lanes per row, 4 rows per load wavefront
    const float4* F = (const float4*)features;
    int col   = lane & 15;           // float4 index within a 64-float row
    int rbase = lane >> 4;           // 0..3
    float4 a = make_float4(0.f, 0.f, 0.f, 0.f);
    if (k == 16) {
        int nid0 = sel_ids[wv][rbase];
        int nid1 = sel_ids[wv][rbase + 4];
        int nid2 = sel_ids[wv][rbase + 8];
        int nid3 = sel_ids[wv][rbase + 12];
        float4 v0 = F[(size_t)nid0 * 16 + col];
        float4 v1 = F[(size_t)nid1 * 16 + col];
        float4 v2 = F[(size_t)nid2 * 16 + col];
        float4 v3 = F[(size_t)nid3 * 16 + col];
        a.x = v0.x + v1.x + v2.x + v3.x;
        a.y = v0.y + v1.y + v2.y + v3.y;
        a.z = v0.z + v1.z + v2.z + v3.z;
        a.w = v0.w + v1.w + v2.w + v3.w;
    } else {
        for (int row0 = 0; row0 < k; row0 += 4) {
            int row = row0 + rbase;
            if (row < k) {
                int nid = sel_ids[wv][row];
                float4 v = F[(size_t)nid * 16 + col];
                a.x += v.x; a.y += v.y; a.z += v.z; a.w += v.w;
            }
        }
    }
    // allreduce across the 4 row-groups (xor 16, 32)
#pragma unroll
    for (int off = 16; off <= 32; off <<= 1) {
        a.x += __shfl_xor(a.x, off);
        a.y += __shfl_xor(a.y, off);
        a.z += __shfl_xor(a.z, off);
        a.w += __shfl_xor(a.w, off);
    }
    float inv_k = 1.f / (float)k;
    a.x *= inv_k; a.y *= inv_k; a.z *= inv_k; a.w *= inv_k;

    // publish agg to LDS (lanes 0-15 hold cols 0..15)
    if (lane < 16) aggl[wv][lane] = a;
    // same-wave producer/consumer: compiler inserts lgkmcnt, no barrier

    // ---- rfeat[e=lane] = relu(sum_j agg[j] * W[j][e]) via uniform LDS reads
    float acc = 0.f;
#pragma unroll
    for (int j4 = 0; j4 < 16; ++j4) {
        float4 ag = aggl[wv][j4];            // wave-uniform -> broadcast
        acc += ag.x * W[(j4 * 4 + 0) * EMB + lane]
             + ag.y * W[(j4 * 4 + 1) * EMB + lane]
             + ag.z * W[(j4 * 4 + 2) * EMB + lane]
             + ag.w * W[(j4 * 4 + 3) * EMB + lane];
    }
    rfeat[((size_t)r * BN + b) * EMB + lane] = fmaxf(acc, 0.f);
}

// ---------------------------------------------------------------- kernel D
// combined[e][b] = relu(cat[b] . weight[:,e]).
// 512 blocks, b-tile = 8. weight read from GLOBAL, coalesced (lane = e,
// row stride 256B); cat in LDS (uniform broadcast).
#define CSTRIDE 264
__global__ __launch_bounds__(256) void final_mm(
    const int* __restrict__ nodes, const float* __restrict__ features,
    const float* __restrict__ rfeat, const float* __restrict__ weight,
    const float* __restrict__ lossacc, const int* __restrict__ smp,
    float* __restrict__ out)
{
    __shared__ float cat_b[8 * CSTRIDE];   // cat_b[bb][i]
    __shared__ float trans[8 * 65];        // output transpose tile
    __shared__ float ls[24];
    int t = threadIdx.x;
    int b0 = blockIdx.x * 8;

    if (blockIdx.x == 0 && t < 24) ls[t] = lossacc[t * 32];

    // stage cat columns: center features then 3 rfeat blocks
    for (int idx = t; idx < 512; idx += 256) {
        int bb = idx >> 6, f = idx & 63;
        cat_b[bb * CSTRIDE + f] = features[(size_t)nodes[b0 + bb] * FEATD + f];
    }
#pragma unroll
    for (int r = 0; r < 3; ++r)
        for (int idx = t; idx < 512; idx += 256) {
            int bb = idx >> 6, j = idx & 63;
            cat_b[bb * CSTRIDE + 64 + r * 64 + j] =
                rfeat[((size_t)r * BN + b0 + bb) * EMB + j];
        }
    __syncthreads();

    int wv = t >> 6, lane = t & 63;     // lane = e
    int bb0 = wv * 2;
    float acc0 = 0.f, acc1 = 0.f;
    const float* c0p = &cat_b[bb0 * CSTRIDE];
    const float* c1p = &cat_b[(bb0 + 1) * CSTRIDE];
    for (int i0 = 0; i0 < 256; i0 += 16) {
        float w[16];
#pragma unroll
        for (int u = 0; u < 16; ++u)
            w[u] = weight[(i0 + u) * EMB + lane];   // coalesced
#pragma unroll
        for (int u = 0; u < 16; ++u) {
            acc0 += w[u] * c0p[i0 + u];             // uniform LDS broadcast
            acc1 += w[u] * c1p[i0 + u];
        }
    }
    trans[bb0 * 65 + lane]       = fmaxf(acc0, 0.f);
    trans[(bb0 + 1) * 65 + lane] = fmaxf(acc1, 0.f);
    __syncthreads();

    // store: out[e][b0..b0+8]
    for (int idx = t; idx < 512; idx += 256) {
        int e = idx >> 3, bb = idx & 7;
        out[(size_t)e * BN + b0 + bb] = trans[bb * 65 + e];
    }

    if (blockIdx.x == 0 && t == 0) {
        int k = smp[0];
        float s = 0.f;
        for (int i = 0; i < 24; ++i) s += ls[i];
        out[(size_t)EMB * BN] = s / (3.f * (float)BN * (float)k);
    }
}

// ----------------------------------------------------------------
extern "C" void kernel_launch(void* const* d_in, const int* in_sizes, int n_in,
                              void* d_out, int out_size, void* d_ws, size_t ws_size,
                              hipStream_t stream) {
    const int*   nodes     = (const int*)  d_in[0];
    // d_in[1] labels: unused
    const int*   neigh1    = (const int*)  d_in[2];
    const int*   neigh2    = (const int*)  d_in[3];
    const int*   neigh3    = (const int*)  d_in[4];
    const int*   pos_nodes = (const int*)  d_in[5];
    const float* features  = (const float*)d_in[6];
    const float* weight    = (const float*)d_in[7];
    const float* rsim      = (const float*)d_in[8];
    const float* pos_embs  = (const float*)d_in[9];
    const float* W1        = (const float*)d_in[10];
    const float* W2        = (const float*)d_in[11];
    const float* W3        = (const float*)d_in[12];
    const int*   smp       = (const int*)  d_in[13];
    float* out = (float*)d_out;
    float* ws  = (float*)d_ws;

    float4* node_sc = (float4*)(ws + WS_SC);
    float*  misc    = ws + WS_MISC;
    float*  lossacc = ws + WS_LOSS;
    float*  rfeat   = ws + WS_RF;

    node_precompute<<<dim3(512), dim3(256), 0, stream>>>(
        features, rsim, pos_embs, node_sc);
    pos_stats<<<dim3(1), dim3(1024), 0, stream>>>(
        pos_nodes, node_sc, pos_embs, misc, lossacc);
    relation_agg<<<dim3(BN / 4, 3), dim3(256), 0, stream>>>(
        neigh1, neigh2, neigh3, features, node_sc, W1, W2, W3,
        misc, lossacc, rfeat, smp);
    final_mm<<<dim3(BN / 8), dim3(256), 0, stream>>>(
        nodes, features, rfeat, weight, lossacc, smp, out);
}

// Round 12
// 70.055 us; speedup vs baseline: 1.3669x; 1.2295x over previous
//
#include <hip/hip_runtime.h>
#include <hip/hip_bf16.h>

#define NN     200000
#define FEATD  64
#define BN     4096
#define DEG    32
#define PP     2048
#define EMB    64
#define EPSV   1e-8f
#define NTILE64 3125       // NN / 64 exactly
#define AWAVES  2048       // 512 blocks x 4 waves

// ws layout (float offsets)
#define WS_SC    0          // float4[NN]  {s0,s1,s2,norm}
#define WS_MISC  800000     // [0..2]=mean_pos  [4..6]=inv_pe
#define WS_LOSS  800064     // 24 slots, stride 32 floats (128B apart)
#define WS_RF    800832     // [3][BN][EMB]

typedef short  bf16x8 __attribute__((ext_vector_type(8)));
typedef float  f32x4  __attribute__((ext_vector_type(4)));

// RNE f32 -> bf16 (returns rounded bits in high 16, mask applied)
__device__ __forceinline__ unsigned int bfr(float x) {
    unsigned int u = __float_as_uint(x);
    return (u + 0x7FFFu + ((u >> 16) & 1u)) & 0xFFFF0000u;
}

// ---------------------------------------------------------------- kernel A
// sim = relu(F @ R) per node; {dot(pe_r,sim)}_r, ||sim|| via MFMA.
// hi/lo bf16 split (3 MFMA passes) => fp32-grade precision (~4e-6 rel).
// Wave-private tile of 64 nodes: F staged coalesced, RNE-split into LDS
// [kg][node^kg] (min-aliasing reads AND writes); R hi/lo fragments in VGPRs
// reused across all 4 M-frags; 96 x mfma_f32_16x16x32_bf16 per tile.
// C/D layout (HW-verified): col=lane&15 (j), row=(lane>>4)*4+reg (node).
// No barriers. LDS 64KB -> 2 blocks/CU.
__global__ __launch_bounds__(256, 2) void node_precompute(
    const float* __restrict__ features, const float* __restrict__ rsim,
    const float* __restrict__ pos_embs, float4* __restrict__ node_sc)
{
    __shared__ unsigned int lds[4][2][8][64][4];   // [wave][hi/lo][kg][node'][16B]
    int t = threadIdx.x, w = t >> 6, l = t & 63;
    int lg = l >> 4;          // k-group / node-group-of-4
    int lr = l & 15;          // A-row / B-col within fragment
    const float4* Gf = (const float4*)features;

    // ---- R fragments (hi/lo), loaded once per wave, reused per tile
    bf16x8 rhi[2][4], rlo[2][4];
#pragma unroll
    for (int kk = 0; kk < 2; ++kk)
#pragma unroll
        for (int nf = 0; nf < 4; ++nf) {
            union { unsigned int u[4]; bf16x8 v; } H, L;
#pragma unroll
            for (int i = 0; i < 4; ++i) {
                int k0 = kk * 32 + lg * 8 + i * 2;
                int j  = nf * 16 + lr;
                float x0 = rsim[k0 * 64 + j];
                float x1 = rsim[(k0 + 1) * 64 + j];
                unsigned int r0 = bfr(x0), r1 = bfr(x1);
                H.u[i] = (r0 >> 16) | r1;
                float l0 = x0 - __uint_as_float(r0);
                float l1 = x1 - __uint_as_float(r1);
                L.u[i] = (__float_as_uint(l0) >> 16)
                       | (__float_as_uint(l1) & 0xFFFF0000u);
            }
            rhi[kk][nf] = H.v; rlo[kk][nf] = L.v;
        }

    float pe[3][4];
#pragma unroll
    for (int rr = 0; rr < 3; ++rr)
#pragma unroll
        for (int nf = 0; nf < 4; ++nf)
            pe[rr][nf] = pos_embs[rr * 64 + nf * 16 + lr];

    unsigned int (*Lhi)[64][4] = lds[w][0];
    unsigned int (*Llo)[64][4] = lds[w][1];

    for (int tile = blockIdx.x * 4 + w; tile < NTILE64; tile += AWAVES) {
        const float4* src = Gf + (size_t)tile * 1024;

        // ---- stage: coalesced load + RNE hi / trunc lo split -> LDS
#pragma unroll
        for (int s = 0; s < 16; ++s) {
            float4 v = src[s * 64 + l];
            int node = s * 4 + lg;
            int kg = lr >> 1, half = lr & 1;
            unsigned int rx = bfr(v.x), ry = bfr(v.y);
            unsigned int rz = bfr(v.z), rw = bfr(v.w);
            unsigned int h0 = (rx >> 16) | ry;
            unsigned int h1 = (rz >> 16) | rw;
            float lx = v.x - __uint_as_float(rx), ly = v.y - __uint_as_float(ry);
            float lz = v.z - __uint_as_float(rz), lw = v.w - __uint_as_float(rw);
            unsigned int l0 = (__float_as_uint(lx) >> 16)
                            | (__float_as_uint(ly) & 0xFFFF0000u);
            unsigned int l1 = (__float_as_uint(lz) >> 16)
                            | (__float_as_uint(lw) & 0xFFFF0000u);
            uint2* dh = (uint2*)&Lhi[kg][node ^ kg][half * 2];
            uint2* dl = (uint2*)&Llo[kg][node ^ kg][half * 2];
            *dh = make_uint2(h0, h1);
            *dl = make_uint2(l0, l1);
        }
        // same-wave producer/consumer: compiler orders via lgkmcnt

        const bf16x8* ph = (const bf16x8*)Lhi;
        const bf16x8* pl = (const bf16x8*)Llo;

#pragma unroll
        for (int mf = 0; mf < 4; ++mf) {
            int node = mf * 16 + lr;
            bf16x8 ah0 = ph[lg * 64 + (node ^ lg)];
            bf16x8 ah1 = ph[(4 + lg) * 64 + (node ^ (4 + lg))];
            bf16x8 al0 = pl[lg * 64 + (node ^ lg)];
            bf16x8 al1 = pl[(4 + lg) * 64 + (node ^ (4 + lg))];

            f32x4 acc[4];
#pragma unroll
            for (int nf = 0; nf < 4; ++nf) acc[nf] = (f32x4)(0.f);
#pragma unroll
            for (int nf = 0; nf < 4; ++nf) {
                acc[nf] = __builtin_amdgcn_mfma_f32_16x16x32_bf16(
                              ah0, rhi[0][nf], acc[nf], 0, 0, 0);
                acc[nf] = __builtin_amdgcn_mfma_f32_16x16x32_bf16(
                              ah1, rhi[1][nf], acc[nf], 0, 0, 0);
                acc[nf] = __builtin_amdgcn_mfma_f32_16x16x32_bf16(
                              ah0, rlo[0][nf], acc[nf], 0, 0, 0);
                acc[nf] = __builtin_amdgcn_mfma_f32_16x16x32_bf16(
                              ah1, rlo[1][nf], acc[nf], 0, 0, 0);
                acc[nf] = __builtin_amdgcn_mfma_f32_16x16x32_bf16(
                              al0, rhi[0][nf], acc[nf], 0, 0, 0);
                acc[nf] = __builtin_amdgcn_mfma_f32_16x16x32_bf16(
                              al1, rhi[1][nf], acc[nf], 0, 0, 0);
            }

            // ---- epilogue: relu, q/s dots over j, reduce over 16 col-lanes
            float q[4] = {0,0,0,0}, s0[4] = {0,0,0,0};
            float s1[4] = {0,0,0,0}, s2[4] = {0,0,0,0};
#pragma unroll
            for (int reg = 0; reg < 4; ++reg)
#pragma unroll
                for (int nf = 0; nf < 4; ++nf) {
                    float v = fmaxf(acc[nf][reg], 0.f);
                    q[reg]  += v * v;
                    s0[reg] += v * pe[0][nf];
                    s1[reg] += v * pe[1][nf];
                    s2[reg] += v * pe[2][nf];
                }
#pragma unroll
            for (int o = 1; o < 16; o <<= 1)
#pragma unroll
                for (int reg = 0; reg < 4; ++reg) {
                    q[reg]  += __shfl_xor(q[reg],  o);
                    s0[reg] += __shfl_xor(s0[reg], o);
                    s1[reg] += __shfl_xor(s1[reg], o);
                    s2[reg] += __shfl_xor(s2[reg], o);
                }
            if (lr < 4) {          // writer for (group lg, reg = l&3)
                int r = l & 3;
                float o0 = (r==0)?s0[0]:(r==1)?s0[1]:(r==2)?s0[2]:s0[3];
                float o1 = (r==0)?s1[0]:(r==1)?s1[1]:(r==2)?s1[2]:s1[3];
                float o2 = (r==0)?s2[0]:(r==1)?s2[1]:(r==2)?s2[2]:s2[3];
                float oq = (r==0)?q[0] :(r==1)?q[1] :(r==2)?q[2] :q[3];
                int n = tile * 64 + mf * 16 + lg * 4 + r;
                node_sc[n] = make_float4(o0, o1, o2, sqrtf(oq));
            }
        }
    }
}

// ---------------------------------------------------------------- kernel B
// pe inverse norms, mean(pos_scores) per relation, zero loss slots.
__global__ __launch_bounds__(1024) void pos_stats(
    const int* __restrict__ pos_nodes, const float4* __restrict__ node_sc,
    const float* __restrict__ pos_embs, float* __restrict__ misc,
    float* __restrict__ lossacc)
{
    __shared__ float invpe_s[3];
    __shared__ float wsum[16][3];
    int t = threadIdx.x, wv = t >> 6, lane = t & 63;

    if (t < 24) lossacc[t * 32] = 0.f;           // zero spread loss slots

    // pe norms: waves 0..2 each own one pos_emb row
    float pv = (t < 192) ? pos_embs[t] : 0.f;
    float q = pv * pv;
#pragma unroll
    for (int off = 32; off; off >>= 1) q += __shfl_down(q, off);
    if (t < 192 && lane == 0) {
        float inv = 1.f / fmaxf(sqrtf(q), EPSV);
        invpe_s[wv] = inv;
        misc[4 + wv] = inv;
    }
    __syncthreads();

    float i0 = invpe_s[0], i1 = invpe_s[1], i2 = invpe_s[2];
    float s0 = 0.f, s1 = 0.f, s2 = 0.f;
    for (int p = t; p < PP; p += 1024) {
        int n = pos_nodes[p];
        float4 sc = node_sc[n];
        float invn = 1.f / fmaxf(sc.w, EPSV);
        s0 += sc.x * i0 * invn;
        s1 += sc.y * i1 * invn;
        s2 += sc.z * i2 * invn;
    }
#pragma unroll
    for (int off = 32; off; off >>= 1) {
        s0 += __shfl_down(s0, off);
        s1 += __shfl_down(s1, off);
        s2 += __shfl_down(s2, off);
    }
    if (lane == 0) { wsum[wv][0] = s0; wsum[wv][1] = s1; wsum[wv][2] = s2; }
    __syncthreads();
    if (t < 3) {
        float s = 0.f;
        for (int w = 0; w < 16; ++w) s += wsum[w][t];
        misc[t] = s / (float)PP;
    }
}

// ---------------------------------------------------------------- kernel C
// One wave per (b, r): score 32 neighbors, stable top-k, parallel 16-row
// feature aggregate, rfeat = relu(agg @ W_r) via uniform-LDS broadcast.
__global__ __launch_bounds__(256) void relation_agg(
    const int* __restrict__ n1, const int* __restrict__ n2, const int* __restrict__ n3,
    const float* __restrict__ features, const float4* __restrict__ node_sc,
    const float* __restrict__ W1, const float* __restrict__ W2, const float* __restrict__ W3,
    const float* __restrict__ misc, float* __restrict__ lossacc,
    float* __restrict__ rfeat, const int* __restrict__ smp)
{
    int r = blockIdx.y;
    const int*   neigh = (r == 0) ? n1 : (r == 1) ? n2 : n3;
    const float* W     = (r == 0) ? W1 : (r == 1) ? W2 : W3;
    int k = smp[0];
    int t = threadIdx.x;
    int wv = t >> 6, lane = t & 63;
    int b = blockIdx.x * 4 + wv;
    float inv_pe   = misc[4 + r];
    float mean_pos = misc[r];

    __shared__ int sel_ids[4][32];
    __shared__ float4 aggl[4][16];

    // ---- score phase (lanes 0-31)
    float s = -1e30f;
    int   n = 0;
    if (lane < 32) {
        n = neigh[b * DEG + lane];
        float4 sc = node_sc[n];
        float num = (r == 0) ? sc.x : (r == 1) ? sc.y : sc.z;
        s = num * inv_pe / fmaxf(sc.w, EPSV);
    }
    // stable rank among 32 scores (ties -> lower index), matches lax.top_k
    int cnt = 0;
#pragma unroll
    for (int d2 = 0; d2 < 32; ++d2) {
        float v = __shfl(s, d2);
        cnt += ((v > s) || (v == s && d2 < lane)) ? 1 : 0;
    }
    bool sel = (lane < 32) && (cnt < k);
    if (sel) sel_ids[wv][cnt] = n;       // rank = unique slot in [0,k)

    float lv = sel ? (s - mean_pos) * (s - mean_pos) : 0.f;
#pragma unroll
    for (int off = 32; off; off >>= 1) lv += __shfl_down(lv, off);
    if (lane == 0)
        atomicAdd(&lossacc[(r * 8 + (blockIdx.x & 7)) * 32], lv);
    // no __syncthreads: sel_ids producer/consumer are the same wave (lgkmcnt)

    // ---- aggregate phase: 16 lanes per row, 4 rows per load wavefront
    const float4* F = (const float4*)features;
    int col   = lane & 15;           // float4 index within a 64-float row
    int rbase = lane >> 4;           // 0..3
    float4 a = make_float4(0.f, 0.f, 0.f, 0.f);
    if (k == 16) {
        int nid0 = sel_ids[wv][rbase];
        int nid1 = sel_ids[wv][rbase + 4];
        int nid2 = sel_ids[wv][rbase + 8];
        int nid3 = sel_ids[wv][rbase + 12];
        float4 v0 = F[(size_t)nid0 * 16 + col];
        float4 v1 = F[(size_t)nid1 * 16 + col];
        float4 v2 = F[(size_t)nid2 * 16 + col];
        float4 v3 = F[(size_t)nid3 * 16 + col];
        a.x = v0.x + v1.x + v2.x + v3.x;
        a.y = v0.y + v1.y + v2.y + v3.y;
        a.z = v0.z + v1.z + v2.z + v3.z;
        a.w = v0.w + v1.w + v2.w + v3.w;
    } else {
        for (int row0 = 0; row0 < k; row0 += 4) {
            int row = row0 + rbase;
            if (row < k) {
                int nid = sel_ids[wv][row];
                float4 v = F[(size_t)nid * 16 + col];
                a.x += v.x; a.y += v.y; a.z += v.z; a.w += v.w;
            }
        }
    }
    // allreduce across the 4 row-groups (xor 16, 32)
#pragma unroll
    for (int off = 16; off <= 32; off <<= 1) {
        a.x += __shfl_xor(a.x, off);
        a.y += __shfl_xor(a.y, off);
        a.z += __shfl_xor(a.z, off);
        a.w += __shfl_xor(a.w, off);
    }
    float inv_k = 1.f / (float)k;
    a.x *= inv_k; a.y *= inv_k; a.z *= inv_k; a.w *= inv_k;

    // publish agg to LDS (lanes 0-15 hold cols 0..15)
    if (lane < 16) aggl[wv][lane] = a;
    // same-wave producer/consumer: compiler inserts lgkmcnt, no barrier

    // ---- rfeat[e=lane] = relu(sum_j agg[j] * W[j][e]) via uniform LDS reads
    float acc = 0.f;
#pragma unroll
    for (int j4 = 0; j4 < 16; ++j4) {
        float4 ag = aggl[wv][j4];            // wave-uniform -> broadcast
        acc += ag.x * W[(j4 * 4 + 0) * EMB + lane]
             + ag.y * W[(j4 * 4 + 1) * EMB + lane]
             + ag.z * W[(j4 * 4 + 2) * EMB + lane]
             + ag.w * W[(j4 * 4 + 3) * EMB + lane];
    }
    rfeat[((size_t)r * BN + b) * EMB + lane] = fmaxf(acc, 0.f);
}

// ---------------------------------------------------------------- kernel D
// combined[e][b] = relu(cat[b] . weight[:,e]).
// 512 blocks, b-tile = 8. weight read from GLOBAL, coalesced (lane = e,
// row stride 256B); cat in LDS (uniform broadcast).
#define CSTRIDE 264
__global__ __launch_bounds__(256) void final_mm(
    const int* __restrict__ nodes, const float* __restrict__ features,
    const float* __restrict__ rfeat, const float* __restrict__ weight,
    const float* __restrict__ lossacc, const int* __restrict__ smp,
    float* __restrict__ out)
{
    __shared__ float cat_b[8 * CSTRIDE];   // cat_b[bb][i]
    __shared__ float trans[8 * 65];        // output transpose tile
    __shared__ float ls[24];
    int t = threadIdx.x;
    int b0 = blockIdx.x * 8;

    if (blockIdx.x == 0 && t < 24) ls[t] = lossacc[t * 32];

    // stage cat columns: center features then 3 rfeat blocks
    for (int idx = t; idx < 512; idx += 256) {
        int bb = idx >> 6, f = idx & 63;
        cat_b[bb * CSTRIDE + f] = features[(size_t)nodes[b0 + bb] * FEATD + f];
    }
#pragma unroll
    for (int r = 0; r < 3; ++r)
        for (int idx = t; idx < 512; idx += 256) {
            int bb = idx >> 6, j = idx & 63;
            cat_b[bb * CSTRIDE + 64 + r * 64 + j] =
                rfeat[((size_t)r * BN + b0 + bb) * EMB + j];
        }
    __syncthreads();

    int wv = t >> 6, lane = t & 63;     // lane = e
    int bb0 = wv * 2;
    float acc0 = 0.f, acc1 = 0.f;
    const float* c0p = &cat_b[bb0 * CSTRIDE];
    const float* c1p = &cat_b[(bb0 + 1) * CSTRIDE];
    for (int i0 = 0; i0 < 256; i0 += 16) {
        float w[16];
#pragma unroll
        for (int u = 0; u < 16; ++u)
            w[u] = weight[(i0 + u) * EMB + lane];   // coalesced
#pragma unroll
        for (int u = 0; u < 16; ++u) {
            acc0 += w[u] * c0p[i0 + u];             // uniform LDS broadcast
            acc1 += w[u] * c1p[i0 + u];
        }
    }
    trans[bb0 * 65 + lane]       = fmaxf(acc0, 0.f);
    trans[(bb0 + 1) * 65 + lane] = fmaxf(acc1, 0.f);
    __syncthreads();

    // store: out[e][b0..b0+8]
    for (int idx = t; idx < 512; idx += 256) {
        int e = idx >> 3, bb = idx & 7;
        out[(size_t)e * BN + b0 + bb] = trans[bb * 65 + e];
    }

    if (blockIdx.x == 0 && t == 0) {
        int k = smp[0];
        float s = 0.f;
        for (int i = 0; i < 24; ++i) s += ls[i];
        out[(size_t)EMB * BN] = s / (3.f * (float)BN * (float)k);
    }
}

// ----------------------------------------------------------------
extern "C" void kernel_launch(void* const* d_in, const int* in_sizes, int n_in,
                              void* d_out, int out_size, void* d_ws, size_t ws_size,
                              hipStream_t stream) {
    const int*   nodes     = (const int*)  d_in[0];
    // d_in[1] labels: unused
    const int*   neigh1    = (const int*)  d_in[2];
    const int*   neigh2    = (const int*)  d_in[3];
    const int*   neigh3    = (const int*)  d_in[4];
    const int*   pos_nodes = (const int*)  d_in[5];
    const float* features  = (const float*)d_in[6];
    const float* weight    = (const float*)d_in[7];
    const float* rsim      = (const float*)d_in[8];
    const float* pos_embs  = (const float*)d_in[9];
    const float* W1        = (const float*)d_in[10];
    const float* W2        = (const float*)d_in[11];
    const float* W3        = (const float*)d_in[12];
    const int*   smp       = (const int*)  d_in[13];
    float* out = (float*)d_out;
    float* ws  = (float*)d_ws;

    float4* node_sc = (float4*)(ws + WS_SC);
    float*  misc    = ws + WS_MISC;
    float*  lossacc = ws + WS_LOSS;
    float*  rfeat   = ws + WS_RF;

    node_precompute<<<dim3(512), dim3(256), 0, stream>>>(
        features, rsim, pos_embs, node_sc);
    pos_stats<<<dim3(1), dim3(1024), 0, stream>>>(
        pos_nodes, node_sc, pos_embs, misc, lossacc);
    relation_agg<<<dim3(BN / 4, 3), dim3(256), 0, stream>>>(
        neigh1, neigh2, neigh3, features, node_sc, W1, W2, W3,
        misc, lossacc, rfeat, smp);
    final_mm<<<dim3(BN / 8), dim3(256), 0, stream>>>(
        nodes, features, rfeat, weight, lossacc, smp, out);
}

// Round 13
// 68.263 us; speedup vs baseline: 1.4027x; 1.0263x over previous
//
#include <hip/hip_runtime.h>
#include <hip/hip_bf16.h>

#define NN     200000
#define FEATD  64
#define BN     4096
#define DEG    32
#define PP     2048
#define EMB    64
#define EPSV   1e-8f
#define NTILE64 3125       // NN / 64 exactly
#define AWAVES  2048       // 512 blocks x 4 waves

// ws layout (float offsets)
#define WS_SC    0          // float4[NN]  {s0,s1,s2,norm}
#define WS_MISC  800000     // [0..2]=mean_pos  [4..6]=inv_pe
#define WS_LOSS  800064     // 24 slots, stride 32 floats (128B apart)
#define WS_RF    800832     // [3][BN][EMB]

typedef short  bf16x8 __attribute__((ext_vector_type(8)));
typedef float  f32x4  __attribute__((ext_vector_type(4)));

// RNE f32 -> bf16 (returns rounded bits in high 16, mask applied)
__device__ __forceinline__ unsigned int bfr(float x) {
    unsigned int u = __float_as_uint(x);
    return (u + 0x7FFFu + ((u >> 16) & 1u)) & 0xFFFF0000u;
}

// ---------------------------------------------------------------- kernel A
// sim = relu(F @ R) per node via MFMA, hi/lo bf16 split (6 passes).
// r12 structure + two stall fixes:
//  (1) register prefetch double-buffer: next tile's 16 float4 loads issued
//      right after this tile's split+LDS-write; MFMA+epilogue (~2.5k cyc)
//      covers HBM latency. launch_bounds(256,2) -> no VGPR cap spill.
//  (2) LDS-transpose epilogue: 4 ds_write_b128 + 4 ds_read_b128 + 8 shfl
//      per mf instead of 64 shfl+64 add (shuffles are DS-pipe ops; 256/tile
//      was costlier than the 96 MFMAs). Swizzled [16][16] f4: col=(lr+n)&15.
// LDS = 64KB (hi/lo tiles) + 16KB (transpose) = 80KB -> 2 blocks/CU.
__global__ __launch_bounds__(256, 2) void node_precompute(
    const float* __restrict__ features, const float* __restrict__ rsim,
    const float* __restrict__ pos_embs, float4* __restrict__ node_sc)
{
    __shared__ unsigned int lds[4][2][8][64][4];   // [wave][hi/lo][kg][node'][16B]
    __shared__ float4 trp[4][16][16];              // [wave][node][swz col]
    int t = threadIdx.x, w = t >> 6, l = t & 63;
    int lg = l >> 4;          // k-group / node-group-of-4
    int lr = l & 15;          // A-row / B-col within fragment
    const float4* Gf = (const float4*)features;

    // ---- R fragments (hi/lo), loaded once per wave, reused per tile
    bf16x8 rhi[2][4], rlo[2][4];
#pragma unroll
    for (int kk = 0; kk < 2; ++kk)
#pragma unroll
        for (int nf = 0; nf < 4; ++nf) {
            union { unsigned int u[4]; bf16x8 v; } H, L;
#pragma unroll
            for (int i = 0; i < 4; ++i) {
                int k0 = kk * 32 + lg * 8 + i * 2;
                int j  = nf * 16 + lr;
                float x0 = rsim[k0 * 64 + j];
                float x1 = rsim[(k0 + 1) * 64 + j];
                unsigned int r0 = bfr(x0), r1 = bfr(x1);
                H.u[i] = (r0 >> 16) | r1;
                float l0 = x0 - __uint_as_float(r0);
                float l1 = x1 - __uint_as_float(r1);
                L.u[i] = (__float_as_uint(l0) >> 16)
                       | (__float_as_uint(l1) & 0xFFFF0000u);
            }
            rhi[kk][nf] = H.v; rlo[kk][nf] = L.v;
        }

    float pe[3][4];
#pragma unroll
    for (int rr = 0; rr < 3; ++rr)
#pragma unroll
        for (int nf = 0; nf < 4; ++nf)
            pe[rr][nf] = pos_embs[rr * 64 + nf * 16 + lr];

    unsigned int (*Lhi)[64][4] = lds[w][0];
    unsigned int (*Llo)[64][4] = lds[w][1];
    float4 (*T)[16] = trp[w];

    // ---- prologue: prefetch first tile into registers
    float4 vv[16];
    int tile = blockIdx.x * 4 + w;
    if (tile < NTILE64) {
        const float4* src = Gf + (size_t)tile * 1024;
#pragma unroll
        for (int s = 0; s < 16; ++s) vv[s] = src[s * 64 + l];
    }

    for (; tile < NTILE64; tile += AWAVES) {
        // ---- split + write hi/lo -> LDS (consumes vv)
#pragma unroll
        for (int s = 0; s < 16; ++s) {
            float4 v = vv[s];
            int node = s * 4 + lg;
            int kg = lr >> 1, half = lr & 1;
            unsigned int rx = bfr(v.x), ry = bfr(v.y);
            unsigned int rz = bfr(v.z), rw = bfr(v.w);
            unsigned int h0 = (rx >> 16) | ry;
            unsigned int h1 = (rz >> 16) | rw;
            float lx = v.x - __uint_as_float(rx), ly = v.y - __uint_as_float(ry);
            float lz = v.z - __uint_as_float(rz), lw = v.w - __uint_as_float(rw);
            unsigned int l0 = (__float_as_uint(lx) >> 16)
                            | (__float_as_uint(ly) & 0xFFFF0000u);
            unsigned int l1 = (__float_as_uint(lz) >> 16)
                            | (__float_as_uint(lw) & 0xFFFF0000u);
            uint2* dh = (uint2*)&Lhi[kg][node ^ kg][half * 2];
            uint2* dl = (uint2*)&Llo[kg][node ^ kg][half * 2];
            *dh = make_uint2(h0, h1);
            *dl = make_uint2(l0, l1);
        }

        // ---- prefetch next tile (vv dead; lands during MFMA+epilogue)
        int nt = tile + AWAVES;
        if (nt < NTILE64) {
            const float4* src = Gf + (size_t)nt * 1024;
#pragma unroll
            for (int s = 0; s < 16; ++s) vv[s] = src[s * 64 + l];
        }

        const bf16x8* ph = (const bf16x8*)Lhi;
        const bf16x8* pl = (const bf16x8*)Llo;

#pragma unroll
        for (int mf = 0; mf < 4; ++mf) {
            int node = mf * 16 + lr;
            bf16x8 ah0 = ph[lg * 64 + (node ^ lg)];
            bf16x8 ah1 = ph[(4 + lg) * 64 + (node ^ (4 + lg))];
            bf16x8 al0 = pl[lg * 64 + (node ^ lg)];
            bf16x8 al1 = pl[(4 + lg) * 64 + (node ^ (4 + lg))];

            f32x4 acc[4];
#pragma unroll
            for (int nf = 0; nf < 4; ++nf) acc[nf] = (f32x4)(0.f);
#pragma unroll
            for (int nf = 0; nf < 4; ++nf) {
                acc[nf] = __builtin_amdgcn_mfma_f32_16x16x32_bf16(
                              ah0, rhi[0][nf], acc[nf], 0, 0, 0);
                acc[nf] = __builtin_amdgcn_mfma_f32_16x16x32_bf16(
                              ah1, rhi[1][nf], acc[nf], 0, 0, 0);
                acc[nf] = __builtin_amdgcn_mfma_f32_16x16x32_bf16(
                              ah0, rlo[0][nf], acc[nf], 0, 0, 0);
                acc[nf] = __builtin_amdgcn_mfma_f32_16x16x32_bf16(
                              ah1, rlo[1][nf], acc[nf], 0, 0, 0);
                acc[nf] = __builtin_amdgcn_mfma_f32_16x16x32_bf16(
                              al0, rhi[0][nf], acc[nf], 0, 0, 0);
                acc[nf] = __builtin_amdgcn_mfma_f32_16x16x32_bf16(
                              al1, rhi[1][nf], acc[nf], 0, 0, 0);
            }

            // ---- epilogue: per-reg dots -> LDS transpose -> 4-lane reduce
#pragma unroll
            for (int reg = 0; reg < 4; ++reg) {
                float s0 = 0.f, s1 = 0.f, s2 = 0.f, q = 0.f;
#pragma unroll
                for (int nf = 0; nf < 4; ++nf) {
                    float v = fmaxf(acc[nf][reg], 0.f);
                    s0 += v * pe[0][nf];
                    s1 += v * pe[1][nf];
                    s2 += v * pe[2][nf];
                    q  += v * v;
                }
                int nd = lg * 4 + reg;
                T[nd][(lr + nd) & 15] = make_float4(s0, s1, s2, q);
            }
            // read back: lane (rn, rq) sums lr in [rq*4, rq*4+4)
            int rn = l >> 2, rq = l & 3;
            float4 a0 = T[rn][(rq * 4 + 0 + rn) & 15];
            float4 a1 = T[rn][(rq * 4 + 1 + rn) & 15];
            float4 a2 = T[rn][(rq * 4 + 2 + rn) & 15];
            float4 a3 = T[rn][(rq * 4 + 3 + rn) & 15];
            float sx = a0.x + a1.x + a2.x + a3.x;
            float sy = a0.y + a1.y + a2.y + a3.y;
            float sz = a0.z + a1.z + a2.z + a3.z;
            float sw = a0.w + a1.w + a2.w + a3.w;
#pragma unroll
            for (int o = 1; o < 4; o <<= 1) {
                sx += __shfl_xor(sx, o);
                sy += __shfl_xor(sy, o);
                sz += __shfl_xor(sz, o);
                sw += __shfl_xor(sw, o);
            }
            if (rq == 0)
                node_sc[tile * 64 + mf * 16 + rn] =
                    make_float4(sx, sy, sz, sqrtf(sw));
        }
    }
}

// ---------------------------------------------------------------- kernel B
// pe inverse norms, mean(pos_scores) per relation, zero loss slots.
__global__ __launch_bounds__(1024) void pos_stats(
    const int* __restrict__ pos_nodes, const float4* __restrict__ node_sc,
    const float* __restrict__ pos_embs, float* __restrict__ misc,
    float* __restrict__ lossacc)
{
    __shared__ float invpe_s[3];
    __shared__ float wsum[16][3];
    int t = threadIdx.x, wv = t >> 6, lane = t & 63;

    if (t < 24) lossacc[t * 32] = 0.f;           // zero spread loss slots

    // pe norms: waves 0..2 each own one pos_emb row
    float pv = (t < 192) ? pos_embs[t] : 0.f;
    float q = pv * pv;
#pragma unroll
    for (int off = 32; off; off >>= 1) q += __shfl_down(q, off);
    if (t < 192 && lane == 0) {
        float inv = 1.f / fmaxf(sqrtf(q), EPSV);
        invpe_s[wv] = inv;
        misc[4 + wv] = inv;
    }
    __syncthreads();

    float i0 = invpe_s[0], i1 = invpe_s[1], i2 = invpe_s[2];
    float s0 = 0.f, s1 = 0.f, s2 = 0.f;
    for (int p = t; p < PP; p += 1024) {
        int n = pos_nodes[p];
        float4 sc = node_sc[n];
        float invn = 1.f / fmaxf(sc.w, EPSV);
        s0 += sc.x * i0 * invn;
        s1 += sc.y * i1 * invn;
        s2 += sc.z * i2 * invn;
    }
#pragma unroll
    for (int off = 32; off; off >>= 1) {
        s0 += __shfl_down(s0, off);
        s1 += __shfl_down(s1, off);
        s2 += __shfl_down(s2, off);
    }
    if (lane == 0) { wsum[wv][0] = s0; wsum[wv][1] = s1; wsum[wv][2] = s2; }
    __syncthreads();
    if (t < 3) {
        float s = 0.f;
        for (int w = 0; w < 16; ++w) s += wsum[w][t];
        misc[t] = s / (float)PP;
    }
}

// ---------------------------------------------------------------- kernel C
// One wave per (b, r): score 32 neighbors, stable top-k, parallel 16-row
// feature aggregate, rfeat = relu(agg @ W_r) via uniform-LDS broadcast.
__global__ __launch_bounds__(256) void relation_agg(
    const int* __restrict__ n1, const int* __restrict__ n2, const int* __restrict__ n3,
    const float* __restrict__ features, const float4* __restrict__ node_sc,
    const float* __restrict__ W1, const float* __restrict__ W2, const float* __restrict__ W3,
    const float* __restrict__ misc, float* __restrict__ lossacc,
    float* __restrict__ rfeat, const int* __restrict__ smp)
{
    int r = blockIdx.y;
    const int*   neigh = (r == 0) ? n1 : (r == 1) ? n2 : n3;
    const float* W     = (r == 0) ? W1 : (r == 1) ? W2 : W3;
    int k = smp[0];
    int t = threadIdx.x;
    int wv = t >> 6, lane = t & 63;
    int b = blockIdx.x * 4 + wv;
    float inv_pe   = misc[4 + r];
    float mean_pos = misc[r];

    __shared__ int sel_ids[4][32];
    __shared__ float4 aggl[4][16];

    // ---- score phase (lanes 0-31)
    float s = -1e30f;
    int   n = 0;
    if (lane < 32) {
        n = neigh[b * DEG + lane];
        float4 sc = node_sc[n];
        float num = (r == 0) ? sc.x : (r == 1) ? sc.y : sc.z;
        s = num * inv_pe / fmaxf(sc.w, EPSV);
    }
    // stable rank among 32 scores (ties -> lower index), matches lax.top_k
    int cnt = 0;
#pragma unroll
    for (int d2 = 0; d2 < 32; ++d2) {
        float v = __shfl(s, d2);
        cnt += ((v > s) || (v == s && d2 < lane)) ? 1 : 0;
    }
    bool sel = (lane < 32) && (cnt < k);
    if (sel) sel_ids[wv][cnt] = n;       // rank = unique slot in [0,k)

    float lv = sel ? (s - mean_pos) * (s - mean_pos) : 0.f;
#pragma unroll
    for (int off = 32; off; off >>= 1) lv += __shfl_down(lv, off);
    if (lane == 0)
        atomicAdd(&lossacc[(r * 8 + (blockIdx.x & 7)) * 32], lv);
    // no __syncthreads: sel_ids producer/consumer are the same wave (lgkmcnt)

    // ---- aggregate phase: 16 lanes per row, 4 rows per load wavefront
    const float4* F = (const float4*)features;
    int col   = lane & 15;           // float4 index within a 64-float row
    int rbase = lane >> 4;           // 0..3
    float4 a = make_float4(0.f, 0.f, 0.f, 0.f);
    if (k == 16) {
        int nid0 = sel_ids[wv][rbase];
        int nid1 = sel_ids[wv][rbase + 4];
        int nid2 = sel_ids[wv][rbase + 8];
        int nid3 = sel_ids[wv][rbase + 12];
        float4 v0 = F[(size_t)nid0 * 16 + col];
        float4 v1 = F[(size_t)nid1 * 16 + col];
        float4 v2 = F[(size_t)nid2 * 16 + col];
        float4 v3 = F[(size_t)nid3 * 16 + col];
        a.x = v0.x + v1.x + v2.x + v3.x;
        a.y = v0.y + v1.y + v2.y + v3.y;
        a.z = v0.z + v1.z + v2.z + v3.z;
        a.w = v0.w + v1.w + v2.w + v3.w;
    } else {
        for (int row0 = 0; row0 < k; row0 += 4) {
            int row = row0 + rbase;
            if (row < k) {
                int nid = sel_ids[wv][row];
                float4 v = F[(size_t)nid * 16 + col];
                a.x += v.x; a.y += v.y; a.z += v.z; a.w += v.w;
            }
        }
    }
    // allreduce across the 4 row-groups (xor 16, 32)
#pragma unroll
    for (int off = 16; off <= 32; off <<= 1) {
        a.x += __shfl_xor(a.x, off);
        a.y += __shfl_xor(a.y, off);
        a.z += __shfl_xor(a.z, off);
        a.w += __shfl_xor(a.w, off);
    }
    float inv_k = 1.f / (float)k;
    a.x *= inv_k; a.y *= inv_k; a.z *= inv_k; a.w *= inv_k;

    // publish agg to LDS (lanes 0-15 hold cols 0..15)
    if (lane < 16) aggl[wv][lane] = a;
    // same-wave producer/consumer: compiler inserts lgkmcnt, no barrier

    // ---- rfeat[e=lane] = relu(sum_j agg[j] * W[j][e]) via uniform LDS reads
    float acc = 0.f;
#pragma unroll
    for (int j4 = 0; j4 < 16; ++j4) {
        float4 ag = aggl[wv][j4];            // wave-uniform -> broadcast
        acc += ag.x * W[(j4 * 4 + 0) * EMB + lane]
             + ag.y * W[(j4 * 4 + 1) * EMB + lane]
             + ag.z * W[(j4 * 4 + 2) * EMB + lane]
             + ag.w * W[(j4 * 4 + 3) * EMB + lane];
    }
    rfeat[((size_t)r * BN + b) * EMB + lane] = fmaxf(acc, 0.f);
}

// ---------------------------------------------------------------- kernel D
// combined[e][b] = relu(cat[b] . weight[:,e]).
// 512 blocks, b-tile = 8. weight read from GLOBAL, coalesced (lane = e,
// row stride 256B); cat in LDS (uniform broadcast).
#define CSTRIDE 264
__global__ __launch_bounds__(256) void final_mm(
    const int* __restrict__ nodes, const float* __restrict__ features,
    const float* __restrict__ rfeat, const float* __restrict__ weight,
    const float* __restrict__ lossacc, const int* __restrict__ smp,
    float* __restrict__ out)
{
    __shared__ float cat_b[8 * CSTRIDE];   // cat_b[bb][i]
    __shared__ float trans[8 * 65];        // output transpose tile
    __shared__ float ls[24];
    int t = threadIdx.x;
    int b0 = blockIdx.x * 8;

    if (blockIdx.x == 0 && t < 24) ls[t] = lossacc[t * 32];

    // stage cat columns: center features then 3 rfeat blocks
    for (int idx = t; idx < 512; idx += 256) {
        int bb = idx >> 6, f = idx & 63;
        cat_b[bb * CSTRIDE + f] = features[(size_t)nodes[b0 + bb] * FEATD + f];
    }
#pragma unroll
    for (int r = 0; r < 3; ++r)
        for (int idx = t; idx < 512; idx += 256) {
            int bb = idx >> 6, j = idx & 63;
            cat_b[bb * CSTRIDE + 64 + r * 64 + j] =
                rfeat[((size_t)r * BN + b0 + bb) * EMB + j];
        }
    __syncthreads();

    int wv = t >> 6, lane = t & 63;     // lane = e
    int bb0 = wv * 2;
    float acc0 = 0.f, acc1 = 0.f;
    const float* c0p = &cat_b[bb0 * CSTRIDE];
    const float* c1p = &cat_b[(bb0 + 1) * CSTRIDE];
    for (int i0 = 0; i0 < 256; i0 += 16) {
        float w[16];
#pragma unroll
        for (int u = 0; u < 16; ++u)
            w[u] = weight[(i0 + u) * EMB + lane];   // coalesced
#pragma unroll
        for (int u = 0; u < 16; ++u) {
            acc0 += w[u] * c0p[i0 + u];             // uniform LDS broadcast
            acc1 += w[u] * c1p[i0 + u];
        }
    }
    trans[bb0 * 65 + lane]       = fmaxf(acc0, 0.f);
    trans[(bb0 + 1) * 65 + lane] = fmaxf(acc1, 0.f);
    __syncthreads();

    // store: out[e][b0..b0+8]
    for (int idx = t; idx < 512; idx += 256) {
        int e = idx >> 3, bb = idx & 7;
        out[(size_t)e * BN + b0 + bb] = trans[bb * 65 + e];
    }

    if (blockIdx.x == 0 && t == 0) {
        int k = smp[0];
        float s = 0.f;
        for (int i = 0; i < 24; ++i) s += ls[i];
        out[(size_t)EMB * BN] = s / (3.f * (float)BN * (float)k);
    }
}

// ----------------------------------------------------------------
extern "C" void kernel_launch(void* const* d_in, const int* in_sizes, int n_in,
                              void* d_out, int out_size, void* d_ws, size_t ws_size,
                              hipStream_t stream) {
    const int*   nodes     = (const int*)  d_in[0];
    // d_in[1] labels: unused
    const int*   neigh1    = (const int*)  d_in[2];
    const int*   neigh2    = (const int*)  d_in[3];
    const int*   neigh3    = (const int*)  d_in[4];
    const int*   pos_nodes = (const int*)  d_in[5];
    const float* features  = (const float*)d_in[6];
    const float* weight    = (const float*)d_in[7];
    const float* rsim      = (const float*)d_in[8];
    const float* pos_embs  = (const float*)d_in[9];
    const float* W1        = (const float*)d_in[10];
    const float* W2        = (const float*)d_in[11];
    const float* W3        = (const float*)d_in[12];
    const int*   smp       = (const int*)  d_in[13];
    float* out = (float*)d_out;
    float* ws  = (float*)d_ws;

    float4* node_sc = (float4*)(ws + WS_SC);
    float*  misc    = ws + WS_MISC;
    float*  lossacc = ws + WS_LOSS;
    float*  rfeat   = ws + WS_RF;

    node_precompute<<<dim3(512), dim3(256), 0, stream>>>(
        features, rsim, pos_embs, node_sc);
    pos_stats<<<dim3(1), dim3(1024), 0, stream>>>(
        pos_nodes, node_sc, pos_embs, misc, lossacc);
    relation_agg<<<dim3(BN / 4, 3), dim3(256), 0, stream>>>(
        neigh1, neigh2, neigh3, features, node_sc, W1, W2, W3,
        misc, lossacc, rfeat, smp);
    final_mm<<<dim3(BN / 8), dim3(256), 0, stream>>>(
        nodes, features, rfeat, weight, lossacc, smp, out);
}